// Round 13
// baseline (250.721 us; speedup 1.0000x reference)
//
#include <hip/hip_runtime.h>

// ---------------------------------------------------------------------------
// TransVLAD fused pipeline for MI355X (gfx950)
// Shapes: N=32, C=512, H=W=32 (P=1024), E=1024, G=8, D=128, K=64
// out: [N, K*D] fp32 (262144)
//
// R19: Y-factorization deletes K2. agg[k,d] = sum_c W1g[d,c]*Y[k,c] with
// Y[k,c] = sum_p w[k,p]*xhat[p,c]. K4 per cc: S-phase (unchanged dbuf) ->
// softmax/w -> pass-2: re-stream xhat (c-major copy xhat_cp, L2-hot) and
// accumulate Y (64 regs, static-indexed) via MFMA (A=wlds same pattern as
// old agg-A; B=X same as old xglds read). After 4 cc: Y->bf16->Ylds
// (row-key swizzle), then agg = Y*W1g^T streaming W1g slices (K2-As
// pattern). Eliminates xe (64MB W + 64MB R) and the 47us K2 kernel;
// halves xg-path flops. k1 = R16-verified + xhat_cp stores (c-major,
// coalesced 128B). k0/k5 byte-identical R16. K2-dbuf stays retired.
// R18 lesson: R17's "k1 87us/138MB" was an atomic-K4 artifact; k1 reverted.
// ---------------------------------------------------------------------------

#define N_  32
#define C_  512
#define P_  1024
#define E_  1024
#define G_  8
#define D_  128
#define K_  64

typedef __attribute__((ext_vector_type(8))) short bf16x8;
typedef __attribute__((ext_vector_type(4))) float f32x4;

__device__ __forceinline__ unsigned short f2b(float f) {
    union { float f; unsigned u; } v; v.f = f;
    unsigned r = (v.u + 0x7FFFu + ((v.u >> 16) & 1u)) >> 16;
    return (unsigned short)r;
}
__device__ __forceinline__ float b2f(unsigned short h) {
    union { unsigned u; float f; } v; v.u = ((unsigned)h) << 16;
    return v.f;
}

// async global->LDS 16B copy: LDS dest must be wave-uniform base + lane*16
__device__ __forceinline__ void gl_lds16(const void* g, void* l) {
    __builtin_amdgcn_global_load_lds(
        (const __attribute__((address_space(1))) void*)g,
        (__attribute__((address_space(3))) void*)l, 16, 0, 0);
}

#define SB  __builtin_amdgcn_sched_barrier(0)
#define BAR __builtin_amdgcn_s_barrier()
#define WAITV(n_) asm volatile("s_waitcnt vmcnt(" #n_ ")" ::: "memory")

// ---------------------------------------------------------------------------
// K0: (bid<1024) W1 -> bf16 AND V[g][k][c] = sum_d Wc[k][d]*W1[g*128+d][c]
//     (bid in [1024,1152)) Wa[g][c] = sum_e W2[g][e]*W1[e][c], bf16.
__global__ __launch_bounds__(256) void k0_prep(const float* __restrict__ W1,
                                               const float* __restrict__ Wc,
                                               const float* __restrict__ W2,
                                               unsigned short* __restrict__ W1b,
                                               unsigned short* __restrict__ Vb,
                                               unsigned short* __restrict__ Wa) {
    int bid = blockIdx.x;
    int t = threadIdx.x;
    if (bid < 1024) {
        int i0 = bid * 512 + t;
        W1b[i0]       = f2b(W1[i0]);
        W1b[i0 + 256] = f2b(W1[i0 + 256]);
        int ch = bid & 1, k = (bid >> 1) & 63, g = bid >> 7;
        int c = ch * 256 + t;
        float acc = 0.f;
        #pragma unroll 8
        for (int d = 0; d < 128; ++d)
            acc += Wc[k * 128 + d] * W1[(g * 128 + d) * C_ + c];
        Vb[(g * 64 + k) * C_ + c] = f2b(acc);
    } else {
        __shared__ float red[256];
        int idx = bid - 1024;            // 0..127
        int g  = idx >> 4;               // 8 groups
        int c0 = (idx & 15) * 32;        // 16 col-chunks of 32
        int c  = c0 + (t & 31);
        int ec = t >> 5;                 // 8 e-chunks of 128
        float acc = 0.f;
        #pragma unroll 8
        for (int i = 0; i < 128; ++i) {
            int e = ec * 128 + i;
            acc += W2[g * E_ + e] * W1[e * C_ + c];
        }
        red[t] = acc;
        __syncthreads();
        if (t < 32) {
            float s = 0.f;
            #pragma unroll
            for (int j = 0; j < 8; ++j) s += red[j * 32 + t];
            Wa[g * C_ + c0 + t] = f2b(s);
        }
    }
}

// ---------------------------------------------------------------------------
// K1: per-pixel L2 norm + transpose + fused att gate (R16-verified) + NEW:
// also writes xhat_cp[n][c][p] (c-major normalized bf16) for K4's pass 2.
__global__ __launch_bounds__(256) void k1_norm_att(const float* __restrict__ x,
                                                   const unsigned short* __restrict__ Wa,
                                                   unsigned short* __restrict__ xhat_t,
                                                   unsigned short* __restrict__ xhat_cp,
                                                   float* __restrict__ att_s) {
    __shared__ short xc[128 * 256];   // [i][t]: c = (t>>6)*128+i, p = p0+(t&63)
    __shared__ short waL[8 * 512];    // Wa bf16
    __shared__ float attP[2 * 64 * 8];
    __shared__ float red[256];
    int n = blockIdx.y;
    int p0 = blockIdx.x * 64;
    int t = threadIdx.x;
    int ps = t & 63, cs = t >> 6;     // cs is wave-uniform

    #pragma unroll
    for (int i = 0; i < 2; ++i) {
        int ch = i * 256 + t;
        *(bf16x8*)&waL[ch * 8] = *(const bf16x8*)&Wa[ch * 8];
    }

    float ss = 0.f;
    for (int i = 0; i < 128; ++i) {
        float v = x[((size_t)(n * C_ + cs * 128 + i)) * P_ + p0 + ps];
        ss += v * v;
        xc[i * 256 + t] = (short)f2b(v);     // lanes consecutive -> conflict-free
    }
    red[t] = ss;
    __syncthreads();
    if (t < 64) {
        float s = red[t] + red[64 + t] + red[128 + t] + red[192 + t];
        red[t] = 1.0f / fmaxf(sqrtf(s), 1e-12f);   // reuse red for rn
    }
    __syncthreads();

    float r = red[ps];
    float accA[8];
    #pragma unroll
    for (int g = 0; g < 8; ++g) accA[g] = 0.f;

    size_t base = ((size_t)(n * P_ + p0 + ps)) * C_ + cs * 128;
    #pragma unroll
    for (int jj = 0; jj < 16; ++jj) {
        bf16x8 o;
        float xv[8];
        #pragma unroll
        for (int j = 0; j < 8; ++j) {
            xv[j] = b2f((unsigned short)xc[(jj * 8 + j) * 256 + t]) * r;
            o[j] = (short)f2b(xv[j]);
        }
        *(bf16x8*)&xhat_t[base + jj * 8] = o;
        // c-major copy: lanes (ps) consecutive along p -> 128B contiguous/store
        #pragma unroll
        for (int j = 0; j < 8; ++j) {
            int c = cs * 128 + jj * 8 + j;
            xhat_cp[((size_t)(n * C_ + c)) * P_ + p0 + ps] = (unsigned short)o[j];
        }
        #pragma unroll
        for (int g = 0; g < 8; ++g) {
            bf16x8 wa = *(const bf16x8*)&waL[g * 512 + cs * 128 + jj * 8];  // broadcast
            #pragma unroll
            for (int j = 0; j < 8; ++j)
                accA[g] += b2f((unsigned short)wa[j]) * xv[j];
        }
    }

    if (cs & 1) {
        #pragma unroll
        for (int g = 0; g < 8; ++g)
            attP[((cs >> 1) * 64 + ps) * 8 + g] = accA[g];
    }
    __syncthreads();
    if (!(cs & 1)) {
        #pragma unroll
        for (int g = 0; g < 8; ++g)
            attP[((cs >> 1) * 64 + ps) * 8 + g] += accA[g];
    }
    __syncthreads();
    if (cs == 0) {
        #pragma unroll
        for (int g = 0; g < 8; ++g) {
            float s = attP[(0 * 64 + ps) * 8 + g] + attP[(1 * 64 + ps) * 8 + g];
            att_s[((size_t)(n * G_ + g)) * P_ + p0 + ps] = 1.0f / (1.0f + __expf(-s));
        }
    }
}

// ---------------------------------------------------------------------------
// K4 helpers (512-thread)
__device__ __forceinline__ void stage_s(short* sb, const unsigned short* __restrict__ Vb,
                                        const unsigned short* __restrict__ xhat_t,
                                        int g, int n, int p0c, int k0, int t) {
    {
        int row = t >> 3, c8 = t & 7;
        gl_lds16(&Vb[(g * 64 + row) * C_ + k0 + ((c8 ^ (row & 7)) * 8)], &sb[t * 8]);
    }
    #pragma unroll
    for (int i = 0; i < 2; ++i) {
        int ch = i * 512 + t;
        int row = ch >> 3, c8 = ch & 7;
        gl_lds16(&xhat_t[((size_t)(n * P_ + p0c + row)) * C_ + k0 + ((c8 ^ (row & 7)) * 8)],
                 &sb[4096 + ch * 8]);
    }
}

// pass-2 tile: [64c][128p] swizzled, 1024 chunks, 2/thread
__device__ __forceinline__ void stage_x(short* xb, const unsigned short* __restrict__ xhat_cp,
                                        int n, int p0c, int c0, int t) {
    #pragma unroll
    for (int i = 0; i < 2; ++i) {
        int ch = i * 512 + t;
        int row = ch >> 4, c16 = ch & 15;
        gl_lds16(&xhat_cp[((size_t)(n * C_ + c0 + row)) * P_ + p0c + ((c16 ^ (row & 7)) * 8)],
                 &xb[ch * 8]);
    }
}

__device__ __forceinline__ void mfma_s(f32x4 acc[4], const short* sb, int w, int q, int l15) {
    #pragma unroll
    for (int kk = 0; kk < 2; ++kk) {
        bf16x8 af[4], bfr;
        #pragma unroll
        for (int mi = 0; mi < 4; ++mi)
            af[mi] = *(const bf16x8*)&sb[(mi * 16 + l15) * 64 + (((kk * 4 + q) ^ (l15 & 7)) * 8)];
        bfr = *(const bf16x8*)&sb[4096 + (w * 16 + l15) * 64 + (((kk * 4 + q) ^ (l15 & 7)) * 8)];
        #pragma unroll
        for (int mi = 0; mi < 4; ++mi)
            acc[mi] = __builtin_amdgcn_mfma_f32_16x16x32_bf16(af[mi], bfr, acc[mi], 0, 0, 0);
    }
}

// Y-slice MFMA: Ysl[mi] += w[kh*32+mi*16..][p] * X[dq*16+..][p]
__device__ __forceinline__ void mfma_y(f32x4 Ysl[2], const short* wlds, const short* XB,
                                       int kh, int dq, int q, int l15) {
    #pragma unroll
    for (int pk = 0; pk < 4; ++pk) {
        bf16x8 a2[2], bx;
        #pragma unroll
        for (int mi = 0; mi < 2; ++mi)
            a2[mi] = *(const bf16x8*)&wlds[(kh * 32 + mi * 16 + l15) * 136 + pk * 32 + q * 8];
        bx = *(const bf16x8*)&XB[(dq * 16 + l15) * 128 + (((pk * 4 + q) ^ (l15 & 7)) * 8)];
        #pragma unroll
        for (int mi = 0; mi < 2; ++mi)
            Ysl[mi] = __builtin_amdgcn_mfma_f32_16x16x32_bf16(a2[mi], bx, Ysl[mi], 0, 0, 0);
    }
}

// ---------------------------------------------------------------------------
// K4: S -> softmax -> Y accumulation (pass 2) per cc; then agg = Y * W1g^T.
// grid (16, 32) x 512 threads. LDS 80KB, 2 blocks/CU.
__global__ __launch_bounds__(512, 4) void k4_assign_agg(const unsigned short* __restrict__ Vb,
                                                        const unsigned short* __restrict__ W1b,
                                                        const unsigned short* __restrict__ xhat_t,
                                                        const unsigned short* __restrict__ xhat_cp,
                                                        const float* __restrict__ att_s,
                                                        float* __restrict__ agg_part,
                                                        float* __restrict__ wsum_part) {
    __shared__ __align__(16) char smem[81920];
    short* S0   = (short*)smem;                 // 24 KB (S phase)
    short* S1   = (short*)(smem + 24576);       // 24 KB (S phase)
    short* X0   = (short*)smem;                 // 16 KB (pass 2; S dead)
    short* X1   = (short*)(smem + 16384);       // 16 KB (pass 2)
    short* wlds = (short*)(smem + 49152);       // [64][136] 17.4 KB (lives through pass 2)
    short* Ylds = (short*)smem;                 // 64 KB (post-cc; all above dead)
    short* Wg   = (short*)(smem + 65536);       // 16 KB (agg' stream)
    float* wred = (float*)smem;                 // epilogue alias (Ylds dead by then? no -
                                                // wred used after agg' reads Ylds: use Wg end)
    float* wred2 = (float*)(smem + 65536);      // 2.25 KB epilogue alias over Wg (dead)

    // XCD-aware remap (bijective: 512 blocks, 512 % 8 == 0)
    int b = blockIdx.y * 16 + blockIdx.x;
    int work = (b & 7) * 64 + (b >> 3);
    int n = work >> 4, g = work & 7, ph = (work >> 3) & 1;

    int t = threadIdx.x;
    int w = t >> 6, l = t & 63, q = l >> 4, l15 = l & 15;
    int kh = w >> 2, dq = w & 3;

    f32x4 Y[8][2];
    #pragma unroll
    for (int sl = 0; sl < 8; ++sl)
        #pragma unroll
        for (int mi = 0; mi < 2; ++mi)
            Y[sl][mi] = (f32x4){0.f, 0.f, 0.f, 0.f};
    float wsp[16];
    #pragma unroll
    for (int j = 0; j < 16; ++j) wsp[j] = 0.f;

#define RND(CUR, NXT, KN) \
    stage_s(NXT, Vb, xhat_t, g, n, p0c, (KN) * 64, t); \
    WAITV(3); BAR; SB; \
    mfma_s(acc_s, CUR, w, q, l15); \
    BAR; SB;

#define YRND(SL, CUR, NXT, CN) \
    stage_x(NXT, xhat_cp, n, p0c, (CN) * 64, t); \
    WAITV(2); BAR; SB; \
    mfma_y(Y[SL], wlds, CUR, kh, dq, q, l15); \
    BAR; SB;

    #pragma unroll 1
    for (int cc = 0; cc < 4; ++cc) {
        int p0c = ph * 512 + cc * 128;

        float av = att_s[(((size_t)(n * G_ + g)) * P_) + p0c + w * 16 + l15];

        f32x4 acc_s[4];
        #pragma unroll
        for (int mi = 0; mi < 4; ++mi)
            acc_s[mi] = (f32x4){0.f, 0.f, 0.f, 0.f};

        // ---- Phase S: S = Vb[g] (64xC) * xhat^T (Cx128), BK=64, dbuf ----
        stage_s(S0, Vb, xhat_t, g, n, p0c, 0, t);
        RND(S0, S1, 1)
        RND(S1, S0, 2)
        RND(S0, S1, 3)
        RND(S1, S0, 4)
        RND(S0, S1, 5)
        RND(S1, S0, 6)
        RND(S0, S1, 7)
        WAITV(0); BAR; SB;
        mfma_s(acc_s, S1, w, q, l15);
        BAR; SB;

        // ---- softmax over k + gate (wave strip = 16 pixels) -> wlds ----
        {
            float m = -1e30f;
            #pragma unroll
            for (int mi = 0; mi < 4; ++mi)
                #pragma unroll
                for (int r = 0; r < 4; ++r)
                    m = fmaxf(m, acc_s[mi][r]);
            m = fmaxf(m, __shfl_xor(m, 16));
            m = fmaxf(m, __shfl_xor(m, 32));
            float s = 0.f;
            #pragma unroll
            for (int mi = 0; mi < 4; ++mi)
                #pragma unroll
                for (int r = 0; r < 4; ++r) {
                    float e = __expf(acc_s[mi][r] - m);
                    acc_s[mi][r] = e;
                    s += e;
                }
            s += __shfl_xor(s, 16);
            s += __shfl_xor(s, 32);

            float scale = av / s;   // av pre-sigmoided

            #pragma unroll
            for (int mi = 0; mi < 4; ++mi)
                #pragma unroll
                for (int r = 0; r < 4; ++r) {
                    float wv = acc_s[mi][r] * scale;
                    wsp[mi * 4 + r] += wv;
                    wlds[(mi * 16 + q * 4 + r) * 136 + (w * 16 + l15)] = (short)f2b(wv);
                }
        }
        __syncthreads();   // wlds visible; S buffers dead -> X0/X1 usable

        // ---- pass 2: Y[k][c] += w[k][p] * xhat[p][c], 8 c-slices, dbuf ----
        stage_x(X0, xhat_cp, n, p0c, 0, t);
        YRND(0, X0, X1, 1)
        YRND(1, X1, X0, 2)
        YRND(2, X0, X1, 3)
        YRND(3, X1, X0, 4)
        YRND(4, X0, X1, 5)
        YRND(5, X1, X0, 6)
        YRND(6, X0, X1, 7)
        WAITV(0); BAR; SB;
        mfma_y(Y[7], wlds, X1, kh, dq, q, l15);
        BAR; SB;
    }

    // ---- Y -> bf16 -> Ylds[64k][512c] (row-key chunk swizzle) ----
    #pragma unroll
    for (int sl = 0; sl < 8; ++sl)
        #pragma unroll
        for (int mi = 0; mi < 2; ++mi)
            #pragma unroll
            for (int r = 0; r < 4; ++r) {
                int k = kh * 32 + mi * 16 + q * 4 + r;
                int c = sl * 64 + dq * 16 + l15;
                Ylds[k * 512 + (((c >> 3) ^ (k & 7)) * 8) + (c & 7)] = (short)f2b(Y[sl][mi][r]);
            }
    __syncthreads();

    // ---- agg' = Y (64k x 512c) * W1g^T (512c x 128d), 8 streamed rounds ----
    f32x4 acc_a[2][2];
    #pragma unroll
    for (int mi = 0; mi < 2; ++mi)
        #pragma unroll
        for (int ni = 0; ni < 2; ++ni)
            acc_a[mi][ni] = (f32x4){0.f, 0.f, 0.f, 0.f};

    #pragma unroll 1
    for (int ks2 = 0; ks2 < 8; ++ks2) {
        #pragma unroll
        for (int i = 0; i < 2; ++i) {
            int ch = i * 512 + t;
            int row = ch >> 3, c8 = ch & 7;
            gl_lds16(&W1b[((g * 128 + row) * C_) + ks2 * 64 + ((c8 ^ (row & 7)) * 8)],
                     &Wg[ch * 8]);
        }
        WAITV(0); BAR; SB;
        #pragma unroll
        for (int kk = 0; kk < 2; ++kk) {
            bf16x8 ay[2], bw[2];
            #pragma unroll
            for (int mi = 0; mi < 2; ++mi)
                ay[mi] = *(const bf16x8*)&Ylds[(kh * 32 + mi * 16 + l15) * 512
                                               + (((ks2 * 8 + kk * 4 + q) ^ (l15 & 7)) * 8)];
            #pragma unroll
            for (int ni = 0; ni < 2; ++ni)
                bw[ni] = *(const bf16x8*)&Wg[(dq * 32 + ni * 16 + l15) * 64
                                             + (((kk * 4 + q) ^ (l15 & 7)) * 8)];
            #pragma unroll
            for (int mi = 0; mi < 2; ++mi)
                #pragma unroll
                for (int ni = 0; ni < 2; ++ni)
                    acc_a[mi][ni] = __builtin_amdgcn_mfma_f32_16x16x32_bf16(ay[mi], bw[ni], acc_a[mi][ni], 0, 0, 0);
        }
        BAR; SB;
    }

    // ---- epilogue: disjoint partials, no atomics ----
    size_t base = (((size_t)(n * G_ + g)) * 2 + ph) * 64;
    #pragma unroll
    for (int mi = 0; mi < 2; ++mi)
        #pragma unroll
        for (int ni = 0; ni < 2; ++ni)
            #pragma unroll
            for (int r = 0; r < 4; ++r) {
                int k = kh * 32 + mi * 16 + q * 4 + r;
                int d = dq * 32 + ni * 16 + l15;
                agg_part[(base + k) * 128 + d] = acc_a[mi][ni][r];
            }

    // wsum: per-wave k-sums -> LDS (over dead Wg) -> one [64] vector per block
    #pragma unroll
    for (int j = 0; j < 16; ++j) {
        float v = wsp[j];
        v += __shfl_xor(v, 1);
        v += __shfl_xor(v, 2);
        v += __shfl_xor(v, 4);
        v += __shfl_xor(v, 8);
        if (l15 == 0) {
            int k = (j >> 2) * 16 + q * 4 + (j & 3);
            wred2[w * 64 + k] = v;
        }
    }
    __syncthreads();
    if (t < 64) {
        float s = 0.f;
        #pragma unroll
        for (int wv = 0; wv < 8; ++wv)
            s += wred2[wv * 64 + t];
        wsum_part[(((size_t)(n * G_ + g)) * 2 + ph) * 64 + t] = s;
    }
    (void)wred;
}

// ---------------------------------------------------------------------------
// K5: vlad[n][k][d] = sum_{g,ph} agg_part - (sum) * centroids
__global__ __launch_bounds__(256) void k5_final(const float* __restrict__ agg_part,
                                                const float* __restrict__ wsum_part,
                                                const float* __restrict__ centroids,
                                                float* __restrict__ out) {
    int idx = blockIdx.x * 256 + threadIdx.x;
    int d = idx & 127;
    int k = (idx >> 7) & 63;
    int n = idx >> 13;
    float ws = 0.f;
    #pragma unroll
    for (int g = 0; g < 8; ++g)
        #pragma unroll
        for (int ph = 0; ph < 2; ++ph)
            ws += wsum_part[(((size_t)(n * G_ + g)) * 2 + ph) * 64 + k];
    float agg = 0.f;
    #pragma unroll
    for (int g = 0; g < 8; ++g)
        #pragma unroll
        for (int ph = 0; ph < 2; ++ph)
            agg += agg_part[(((((size_t)(n * G_ + g)) * 2 + ph) * 64) + k) * 128 + d];
    out[idx] = agg - ws * centroids[k * 128 + d];
}

// ---------------------------------------------------------------------------
extern "C" void kernel_launch(void* const* d_in, const int* in_sizes, int n_in,
                              void* d_out, int out_size, void* d_ws, size_t ws_size,
                              hipStream_t stream) {
    const float* x         = (const float*)d_in[0];
    const float* W1        = (const float*)d_in[1];
    const float* W2        = (const float*)d_in[2];
    const float* Wc        = (const float*)d_in[3];
    const float* centroids = (const float*)d_in[4];
    float* out = (float*)d_out;

    // Workspace layout (total <= 120,324,096 B proven footprint):
    //   W1b      [E*C]        bf16   1,048,576 B @ 0
    //   Vb       [G*K*C]      bf16     524,288 B @ 1,048,576
    //   xhat_t   [N*P*C]      bf16  33,554,432 B @ 1,572,864
    //   xhat_cp  [N*C*P]      bf16  33,554,432 B @ 35,127,296 (old xe slot)
    //   att_s    [N*G*P]      f32    1,048,576 B @ 102,236,160
    //   agg_part [N*G*2*K*D]  f32   16,777,216 B @ 103,284,736
    //   wsum_part[N*G*2*K]    f32      131,072 B @ 120,061,952
    //   Wa       [G*C]        bf16       8,192 B @ 120,193,024
    char* ws = (char*)d_ws;
    unsigned short* W1b      = (unsigned short*)(ws + 0);
    unsigned short* Vb       = (unsigned short*)(ws + 1048576);
    unsigned short* xhat_t   = (unsigned short*)(ws + 1572864);
    unsigned short* xhat_cp  = (unsigned short*)(ws + 35127296);
    float*          att_s    = (float*)(ws + 102236160);
    float*          agg_part = (float*)(ws + 103284736);
    float*          wsum_part= (float*)(ws + 120061952);
    unsigned short* Wa       = (unsigned short*)(ws + 120193024);

    hipLaunchKernelGGL(k0_prep,        dim3(1152), dim3(256), 0, stream, W1, Wc, W2, W1b, Vb, Wa);
    hipLaunchKernelGGL(k1_norm_att,    dim3(16, 32), dim3(256), 0, stream, x, Wa, xhat_t,
                       xhat_cp, att_s);
    hipLaunchKernelGGL(k4_assign_agg,  dim3(16, 32), dim3(512), 0, stream, Vb, W1b, xhat_t,
                       xhat_cp, att_s, agg_part, wsum_part);
    hipLaunchKernelGGL(k5_final,       dim3(1024), dim3(256), 0, stream,
                       agg_part, wsum_part, centroids, out);
}